// Round 1
// baseline (25236.208 us; speedup 1.0000x reference)
//
#include <hip/hip_runtime.h>
#include <stdint.h>

// ---------------------------------------------------------------------------
// PointNet++ forward, MI355X. Round 1: correctness-first.
//   - FPS: single block per level, register-resident points, 1 barrier/iter.
//   - SA: wave-per-target brute-force radius search + per-neighbor MLP + max.
//   - FP: wave-per-fine-point brute-force 3NN + interp + MLP (+ fused lin_out).
// Numerics: all reference-sensitive math uses explicit RN intrinsics (no
// contraction); sqdist uses the norm-trick formula with a BLAS-style fma
// chain for the 3-dot (DOT_FMA_CHAIN=1). Flip to 0 if absmax shows few-point
// O(0.1) errors (discrete boundary flips).
// ---------------------------------------------------------------------------

#define DOT_FMA_CHAIN 1

#define DEV static __device__ __forceinline__

DEV float fadd_(float a, float b){ return __fadd_rn(a,b); }
DEV float fsub_(float a, float b){ return __fsub_rn(a,b); }
DEV float fmul_(float a, float b){ return __fmul_rn(a,b); }
DEV float fdiv_(float a, float b){ return __fdiv_rn(a,b); }

DEV float dot3(float ax,float ay,float az,float bx,float by,float bz){
#if DOT_FMA_CHAIN
  return fmaf(az,bz, fmaf(ay,by, __fmul_rn(ax,bx)));
#else
  return __fadd_rn(__fadd_rn(__fmul_rn(ax,bx),__fmul_rn(ay,by)),__fmul_rn(az,bz));
#endif
}

// sqdist() norm trick: max(0, (na+nb) - 2*dot)
DEV float sqd(float na, float nb, float d){
  float t = __fadd_rn(na, nb);
  float u = __fmul_rn(2.0f, d);
  return fmaxf(__fsub_rn(t, u), 0.0f);
}

// ---------------------------------------------------------------------------
// prep: pos -> float4(x,y,z,|p|^2)  and  h0 = lin_in MLP(x)  (16->16->16 relu)
// ---------------------------------------------------------------------------
__global__ __launch_bounds__(256) void k_prep(
    const float* __restrict__ x, const float* __restrict__ pos,
    const float* __restrict__ W0, const float* __restrict__ b0,
    const float* __restrict__ W1, const float* __restrict__ b1,
    float4* __restrict__ pos4, float* __restrict__ h_out, int n)
{
  __shared__ float sW0[256], sb0[16], sW1[256], sb1[16];
  int tid = threadIdx.x;
  sW0[tid] = W0[tid];
  sW1[tid] = W1[tid];
  if (tid < 16){ sb0[tid] = b0[tid]; sb1[tid] = b1[tid]; }
  __syncthreads();
  int p = blockIdx.x*256 + tid;
  if (p >= n) return;

  float px = pos[3*p], py = pos[3*p+1], pz = pos[3*p+2];
  float nrm = fadd_(fadd_(fmul_(px,px), fmul_(py,py)), fmul_(pz,pz));
  pos4[p] = make_float4(px,py,pz,nrm);

  const float4* xr = (const float4*)(x + (size_t)p*16);
  float4 v0 = xr[0], v1 = xr[1], v2 = xr[2], v3 = xr[3];
  float xin[16] = {v0.x,v0.y,v0.z,v0.w, v1.x,v1.y,v1.z,v1.w,
                   v2.x,v2.y,v2.z,v2.w, v3.x,v3.y,v3.z,v3.w};
  float h1[16];
  #pragma unroll
  for (int o=0;o<16;o++){
    float acc = fmul_(xin[0], sW0[o]);
    #pragma unroll
    for (int k=1;k<16;k++) acc = fmaf(xin[k], sW0[k*16+o], acc);
    h1[o] = fmaxf(fadd_(acc, sb0[o]), 0.0f);
  }
  float h2[16];
  #pragma unroll
  for (int o=0;o<16;o++){
    float acc = fmul_(h1[0], sW1[o]);
    #pragma unroll
    for (int k=1;k<16;k++) acc = fmaf(h1[k], sW1[k*16+o], acc);
    h2[o] = fmaxf(fadd_(acc, sb1[o]), 0.0f);
  }
  float4* hw = (float4*)(h_out + (size_t)p*16);
  hw[0] = make_float4(h2[0], h2[1], h2[2], h2[3]);
  hw[1] = make_float4(h2[4], h2[5], h2[6], h2[7]);
  hw[2] = make_float4(h2[8], h2[9], h2[10],h2[11]);
  hw[3] = make_float4(h2[12],h2[13],h2[14],h2[15]);
}

// ---------------------------------------------------------------------------
// FPS: n = P*1024 points, single block of 1024 threads, m = n/2 samples.
// Exact replication of reference scan: mind=min(mind,|p-last|^2), argmax
// (first-occurrence = lowest index on ties). Writes sampled float4 in order.
// ---------------------------------------------------------------------------
template<int P>
__global__ __launch_bounds__(1024) void k_fps(
    const float4* __restrict__ src, float4* __restrict__ samp, int m)
{
  __shared__ float wmv[2][16];
  __shared__ int   wmi[2][16];
  const int t = threadIdx.x;
  const int lane = t & 63, wv = t >> 6;

  float px[P], py[P], pz[P], mind[P];
  #pragma unroll
  for (int k=0;k<P;k++){
    float4 v = src[k*1024 + t];
    px[k]=v.x; py[k]=v.y; pz[k]=v.z;
    mind[k] = __builtin_inff();
  }
  float sx, sy, sz;
  { float4 s0 = src[0]; sx=s0.x; sy=s0.y; sz=s0.z;
    if (t==0) samp[0] = s0; }

  for (int i=1;i<m;i++){
    float bv = -1.0f; int bp = 0x7fffffff;
    #pragma unroll
    for (int k=0;k<P;k++){
      float dx = fsub_(px[k],sx), dy = fsub_(py[k],sy), dz = fsub_(pz[k],sz);
      float d2 = fadd_(fadd_(fmul_(dx,dx),fmul_(dy,dy)),fmul_(dz,dz));
      float nm = fminf(mind[k], d2);
      mind[k] = nm;
      bool g = nm > bv;                 // strict >: first (lowest k) wins ties
      bv = g ? nm : bv;
      bp = g ? (k*1024 + t) : bp;
    }
    // wave argmax (value desc, index asc)
    #pragma unroll
    for (int s=1;s<64;s<<=1){
      float ov = __shfl_xor(bv, s);
      int   op = __shfl_xor(bp, s);
      bool tk = (ov > bv) || (ov == bv && op < bp);
      bv = tk ? ov : bv; bp = tk ? op : bp;
    }
    int par = i & 1;
    if (lane == 0){ wmv[par][wv] = bv; wmi[par][wv] = bp; }
    __syncthreads();
    // all waves redundantly reduce the 16 wave maxima (no second barrier)
    float fv = wmv[par][lane & 15];
    int   fpi = wmi[par][lane & 15];
    #pragma unroll
    for (int s=1;s<16;s<<=1){
      float ov = __shfl_xor(fv, s);
      int   op = __shfl_xor(fpi, s);
      bool tk = (ov > fv) || (ov == fv && op < fpi);
      fv = tk ? ov : fv; fpi = tk ? op : fpi;
    }
    float4 wp = src[fpi];          // wave-uniform broadcast load
    sx = wp.x; sy = wp.y; sz = wp.z;
    if (t == 0) samp[i] = wp;
  }
}

// ---------------------------------------------------------------------------
// SA: wave per target. Brute-force radius(<=2) search over all sources with
// ballot-append; exact 32-smallest fallback if >32 in radius. Then per-lane
// neighbor MLP concat(xj[16], rel[3]) -> 19 -> relu -> 16 -> relu, masked
// max over lanes.
// ---------------------------------------------------------------------------
#define SA_CAP 96

__global__ __launch_bounds__(256) void k_sa(
  const float4* __restrict__ spos, int n_src,
  const float4* __restrict__ tpos,
  const float*  __restrict__ F,
  const float* __restrict__ W0, const float* __restrict__ b0,
  const float* __restrict__ W1, const float* __restrict__ b1,
  float* __restrict__ Fout)
{
  __shared__ float sW0[361], sb0[19], sW1[304], sb1[16];
  __shared__ int   nidx[4][SA_CAP];
  __shared__ float nd2[4][SA_CAP];
  int tid = threadIdx.x;
  for (int i=tid;i<361;i+=256) sW0[i]=W0[i];
  for (int i=tid;i<304;i+=256) sW1[i]=W1[i];
  if (tid<19) sb0[tid]=b0[tid];
  if (tid<16) sb1[tid]=b1[tid];
  __syncthreads();

  int wv = tid >> 6, lane = tid & 63;
  int tg = blockIdx.x*4 + wv;
  float4 tp = tpos[tg];

  int cnt = 0;
  for (int base=0; base<n_src; base+=64){
    int j = base + lane;
    float4 sp = spos[j];
    float d2 = sqd(tp.w, sp.w, dot3(tp.x,tp.y,tp.z, sp.x,sp.y,sp.z));
    bool in = (d2 <= 4.0f);
    unsigned long long mk = __ballot(in);
    int pos = cnt + __popcll(mk & ((1ull<<lane)-1ull));
    if (in && pos < SA_CAP){ nidx[wv][pos]=j; nd2[wv][pos]=d2; }
    cnt += __popcll(mk);
  }
  if (cnt > SA_CAP) cnt = SA_CAP;

  if (cnt > 32){
    // rare: pick exact 32 smallest (d2, idx)-lex. All lanes compute the same
    // selection mask redundantly (no cross-lane comms until compaction).
    uint64_t tk0=0, tk1=0;
    for (int r=0;r<32;r++){
      float bvv = 3.5e38f; int bii = 0x7fffffff; int be = 0;
      for (int e=0;e<cnt;e++){
        bool done = (e<64) ? ((tk0>>e)&1ull) : ((tk1>>(e-64))&1ull);
        if (done) continue;
        float dv = nd2[wv][e]; int di = nidx[wv][e];
        if (dv < bvv || (dv == bvv && di < bii)){ bvv=dv; bii=di; be=e; }
      }
      if (be < 64) tk0 |= (1ull<<be); else tk1 |= (1ull<<(be-64));
    }
    int myi = 0; float myd = 0.0f;
    if (lane < 32){
      int seen = 0, sel = -1;
      for (int e=0;e<cnt && sel<0;e++){
        bool s = (e<64) ? ((tk0>>e)&1ull) : ((tk1>>(e-64))&1ull);
        if (s){ if (seen == lane) sel = e; seen++; }
      }
      myi = nidx[wv][sel]; myd = nd2[wv][sel];
    }
    __builtin_amdgcn_wave_barrier();
    if (lane < 32){ nidx[wv][lane]=myi; nd2[wv][lane]=myd; }
    __builtin_amdgcn_wave_barrier();
    cnt = 32;
  }

  float in19[19];
  #pragma unroll
  for (int k=0;k<19;k++) in19[k] = 0.0f;
  if (lane < cnt){
    int j = nidx[wv][lane];
    const float4* fr = (const float4*)(F + (size_t)j*16);
    float4 a=fr[0], b=fr[1], c=fr[2], d=fr[3];
    in19[0]=a.x; in19[1]=a.y; in19[2]=a.z; in19[3]=a.w;
    in19[4]=b.x; in19[5]=b.y; in19[6]=b.z; in19[7]=b.w;
    in19[8]=c.x; in19[9]=c.y; in19[10]=c.z; in19[11]=c.w;
    in19[12]=d.x; in19[13]=d.y; in19[14]=d.z; in19[15]=d.w;
    float4 sp = spos[j];
    in19[16]=fsub_(sp.x,tp.x); in19[17]=fsub_(sp.y,tp.y); in19[18]=fsub_(sp.z,tp.z);
  }
  float h[19];
  #pragma unroll
  for (int o=0;o<19;o++){
    float acc = fmul_(in19[0], sW0[o]);
    #pragma unroll
    for (int k=1;k<19;k++) acc = fmaf(in19[k], sW0[k*19+o], acc);
    h[o] = fmaxf(fadd_(acc, sb0[o]), 0.0f);
  }
  float outv[16];
  #pragma unroll
  for (int o=0;o<16;o++){
    float acc = fmul_(h[0], sW1[o]);
    #pragma unroll
    for (int k=1;k<19;k++) acc = fmaf(h[k], sW1[k*16+o], acc);
    float v = fmaxf(fadd_(acc, sb1[o]), 0.0f);
    outv[o] = (lane < cnt) ? v : -1e30f;
  }
  #pragma unroll
  for (int o=0;o<16;o++){
    float v = outv[o];
    #pragma unroll
    for (int s=1;s<64;s<<=1) v = fmaxf(v, __shfl_xor(v, s));
    outv[o] = v;
  }
  if (lane == 0){
    float4* dst = (float4*)(Fout + (size_t)tg*16);
    dst[0] = make_float4(outv[0], outv[1], outv[2], outv[3]);
    dst[1] = make_float4(outv[4], outv[5], outv[6], outv[7]);
    dst[2] = make_float4(outv[8], outv[9], outv[10],outv[11]);
    dst[3] = make_float4(outv[12],outv[13],outv[14],outv[15]);
  }
}

// ---------------------------------------------------------------------------
// FP: wave per fine point. Brute-force 3NN over coarse set (lane-strided,
// (d2,idx)-lex stable like top_k), inverse-distance weights, interp 16ch,
// concat skip, MLP 32->32->16 (relu both), optionally fused lin_out 16->16
// relu -> 16->2.
// ---------------------------------------------------------------------------
__global__ __launch_bounds__(256) void k_fp(
  const float4* __restrict__ fpos,
  const float4* __restrict__ cpos, int n_coarse,
  const float* __restrict__ Fc, const float* __restrict__ Fs,
  const float* __restrict__ W0, const float* __restrict__ b0,
  const float* __restrict__ W1, const float* __restrict__ b1,
  const float* __restrict__ loW0, const float* __restrict__ lob0,
  const float* __restrict__ loW1, const float* __restrict__ lob1,
  float* __restrict__ outp, int final_)
{
  __shared__ float sW0[1024], sb0[32], sW1[512], sb1[16];
  __shared__ float sLW0[256], sLb0[16], sLW1[32], sLb1[2];
  int tid = threadIdx.x;
  for (int i=tid;i<1024;i+=256) sW0[i]=W0[i];
  for (int i=tid;i<512;i+=256)  sW1[i]=W1[i];
  if (tid<32) sb0[tid]=b0[tid];
  if (tid<16) sb1[tid]=b1[tid];
  if (final_){
    sLW0[tid & 255] = loW0[tid & 255];   // 256 threads cover 256
    if (tid<16) sLb0[tid]=lob0[tid];
    if (tid<32) sLW1[tid]=loW1[tid];
    if (tid<2)  sLb1[tid]=lob1[tid];
  }
  __syncthreads();

  int wv = tid >> 6, lane = tid & 63;
  int f = blockIdx.x*4 + wv;
  float4 fp = fpos[f];

  float c0v=3.5e38f, c1v=3.5e38f, c2v=3.5e38f;
  int   c0i=0x7fffffff, c1i=0x7fffffff, c2i=0x7fffffff;
  for (int j=lane; j<n_coarse; j+=64){
    float4 cp = cpos[j];
    float d2 = sqd(fp.w, cp.w, dot3(fp.x,fp.y,fp.z, cp.x,cp.y,cp.z));
    if (d2 < c2v || (d2 == c2v && j < c2i)){
      bool a0 = (d2 < c0v) || (d2 == c0v && j < c0i);
      bool a1 = (d2 < c1v) || (d2 == c1v && j < c1i);
      c2v = a1 ? c1v : d2;               c2i = a1 ? c1i : j;
      c1v = a0 ? c0v : (a1 ? d2 : c1v);  c1i = a0 ? c0i : (a1 ? j : c1i);
      c0v = a0 ? d2 : c0v;               c0i = a0 ? j  : c0i;
    }
  }
  float nnd[3]; int nni[3];
  #pragma unroll
  for (int r=0;r<3;r++){
    float v = c0v; int idx = c0i;
    #pragma unroll
    for (int s=1;s<64;s<<=1){
      float ov = __shfl_xor(v, s);
      int   oi = __shfl_xor(idx, s);
      bool tk = (ov < v) || (ov == v && oi < idx);
      v = tk ? ov : v; idx = tk ? oi : idx;
    }
    nnd[r] = v; nni[r] = idx;
    if (c0v == v && c0i == idx){   // owner pops its head
      c0v=c1v; c0i=c1i; c1v=c2v; c1i=c2i; c2v=3.5e38f; c2i=0x7fffffff;
    }
  }
  float w0 = fdiv_(1.0f, fmaxf(nnd[0], 1e-16f));
  float w1 = fdiv_(1.0f, fmaxf(nnd[1], 1e-16f));
  float w2 = fdiv_(1.0f, fmaxf(nnd[2], 1e-16f));
  float ws = fadd_(fadd_(w0,w1),w2);
  w0 = fdiv_(w0,ws); w1 = fdiv_(w1,ws); w2 = fdiv_(w2,ws);

  float hv = 0.0f;
  if (lane < 16){
    int c = lane;
    float x0 = Fc[(size_t)nni[0]*16 + c];
    float x1 = Fc[(size_t)nni[1]*16 + c];
    float x2 = Fc[(size_t)nni[2]*16 + c];
    hv = fadd_(fadd_(fmul_(w0,x0), fmul_(w1,x1)), fmul_(w2,x2));
  } else if (lane < 32){
    hv = Fs[(size_t)f*16 + (lane-16)];
  }
  // layer1: 32 -> 32 (o = lane&31)
  int o1 = lane & 31;
  float acc = fmul_(__shfl(hv, 0), sW0[o1]);
  #pragma unroll
  for (int k=1;k<32;k++) acc = fmaf(__shfl(hv, k), sW0[k*32+o1], acc);
  float g1 = fmaxf(fadd_(acc, sb0[o1]), 0.0f);
  // layer2: 32 -> 16 (o = lane&15)
  int o2 = lane & 15;
  float a2 = fmul_(__shfl(g1, 0), sW1[o2]);
  #pragma unroll
  for (int k=1;k<32;k++) a2 = fmaf(__shfl(g1, k), sW1[k*16+o2], a2);
  float g2 = fmaxf(fadd_(a2, sb1[o2]), 0.0f);

  if (!final_){
    if (lane < 16) outp[(size_t)f*16 + lane] = g2;
  } else {
    float a3 = fmul_(__shfl(g2, 0), sLW0[o2]);
    #pragma unroll
    for (int k=1;k<16;k++) a3 = fmaf(__shfl(g2, k), sLW0[k*16+o2], a3);
    float q = fmaxf(fadd_(a3, sLb0[o2]), 0.0f);
    int o3 = lane & 1;
    float a4 = fmul_(__shfl(q, 0), sLW1[o3]);
    #pragma unroll
    for (int k=1;k<16;k++) a4 = fmaf(__shfl(q, k), sLW1[k*2+o3], a4);
    a4 = fadd_(a4, sLb1[o3]);
    if (lane < 2) outp[(size_t)f*2 + lane] = a4;
  }
}

// ---------------------------------------------------------------------------
extern "C" void kernel_launch(void* const* d_in, const int* in_sizes, int n_in,
                              void* d_out, int out_size, void* d_ws, size_t ws_size,
                              hipStream_t stream) {
  (void)in_sizes; (void)n_in; (void)out_size; (void)ws_size;
  const float* x     = (const float*)d_in[0];
  const float* pos   = (const float*)d_in[1];
  const float* liW0  = (const float*)d_in[3];
  const float* lib0  = (const float*)d_in[4];
  const float* liW1  = (const float*)d_in[5];
  const float* lib1  = (const float*)d_in[6];
  const float* saW0  = (const float*)d_in[7];   // [3,19,19]
  const float* sab0  = (const float*)d_in[8];   // [3,19]
  const float* saW1  = (const float*)d_in[9];   // [3,19,16]
  const float* sab1  = (const float*)d_in[10];  // [3,16]
  const float* fpW0  = (const float*)d_in[11];  // [3,32,32]
  const float* fpb0  = (const float*)d_in[12];  // [3,32]
  const float* fpW1  = (const float*)d_in[13];  // [3,32,16]
  const float* fpb1  = (const float*)d_in[14];  // [3,16]
  const float* loW0  = (const float*)d_in[15];
  const float* lob0  = (const float*)d_in[16];
  const float* loW1  = (const float*)d_in[17];
  const float* lob1  = (const float*)d_in[18];
  float* out = (float*)d_out;

  char* ws = (char*)d_ws;
  size_t off = 0;
  auto alloc = [&](size_t bytes)->void* {
    void* p = ws + off;
    off += (bytes + 255) & ~(size_t)255;
    return p;
  };
  float4* P0 = (float4*)alloc(16384u*16);
  float4* P1 = (float4*)alloc(8192u*16);
  float4* P2 = (float4*)alloc(4096u*16);
  float4* P3 = (float4*)alloc(2048u*16);
  float*  F0 = (float*)alloc(16384u*16*4);
  float*  F1 = (float*)alloc(8192u*16*4);
  float*  F2 = (float*)alloc(4096u*16*4);
  float*  F3 = (float*)alloc(2048u*16*4);
  float*  G2 = (float*)alloc(4096u*16*4);
  float*  G1 = (float*)alloc(8192u*16*4);

  // lin_in + pos4/norm prep
  k_prep<<<64,256,0,stream>>>(x,pos, liW0,lib0,liW1,lib1, P0,F0, 16384);

  // SA path
  k_fps<16><<<1,1024,0,stream>>>(P0, P1, 8192);
  k_sa<<<2048,256,0,stream>>>(P0,16384, P1, F0, saW0,      sab0,    saW1,      sab1,    F1);
  k_fps<8><<<1,1024,0,stream>>>(P1, P2, 4096);
  k_sa<<<1024,256,0,stream>>>(P1, 8192, P2, F1, saW0+361,  sab0+19, saW1+304,  sab1+16, F2);
  k_fps<4><<<1,1024,0,stream>>>(P2, P3, 2048);
  k_sa<<< 512,256,0,stream>>>(P2, 4096, P3, F2, saW0+722,  sab0+38, saW1+608,  sab1+32, F3);

  // FP path (level 2 -> 0; level 0 fuses lin_out and writes d_out)
  k_fp<<<1024,256,0,stream>>>(P2, P3,2048, F3, F2,
      fpW0+2048, fpb0+64, fpW1+1024, fpb1+32,
      loW0,lob0,loW1,lob1, G2, 0);
  k_fp<<<2048,256,0,stream>>>(P1, P2,4096, G2, F1,
      fpW0+1024, fpb0+32, fpW1+512,  fpb1+16,
      loW0,lob0,loW1,lob1, G1, 0);
  k_fp<<<4096,256,0,stream>>>(P0, P1,8192, G1, F0,
      fpW0,      fpb0,    fpW1,      fpb1,
      loW0,lob0,loW1,lob1, out, 1);
}